// Round 1
// baseline (1131.998 us; speedup 1.0000x reference)
//
#include <hip/hip_runtime.h>

#define Bn   32
#define HIN  56
#define WIN  56
#define Cc   256
#define HG   28
#define WG   28

#define GIN_SIZE (Bn*HIN*WIN*Cc)        // 25690112
#define GW_SIZE  (9*Cc*Cc)              // 589824
#define GW_OFF   GIN_SIZE
#define BIAS_OFF (GW_OFF + GW_SIZE)     // 26279936

__global__ __launch_bounds__(256) void k_zero(float* __restrict__ p, int n) {
    int i = blockIdx.x * 256 + threadIdx.x;
    if (i < n) p[i] = 0.f;
}

// grad_in: transposed conv, decomposed by output parity class.
// grid = (392 pixel-tiles of 64, 4 classes), block = 256.
// Per block: 64 pixels x 256 ci. K = taps(1,2,4) x 256 co.
__global__ __launch_bounds__(256) void k_grad_in(
    const float* __restrict__ g,      // [32,28,28,256]
    const float* __restrict__ wt,     // [3,3,256,256] (ci,co innermost)
    float* __restrict__ out)          // [32,56,56,256]
{
    __shared__ float w_lds[16][256];  // [co][ci]
    __shared__ float g_lds[16][64];   // [co][pix]

    const int t   = threadIdx.x;
    const int cls = blockIdx.y;
    const int dy = cls >> 1, dx = cls & 1;
    const int tile = blockIdx.x;

    const int cg  = t & 63;           // ci group (4 ci each)
    const int pg  = t >> 6;           // pixel group (16 pix each)
    const int ci0 = cg * 4;

    const int p_stage = t & 63;       // staging: one pixel per thread slot
    const int co_off  = (t >> 6) * 4; // staging: 4 co per thread

    float acc[16][4];
    #pragma unroll
    for (int p = 0; p < 16; ++p)
        #pragma unroll
        for (int c = 0; c < 4; ++c) acc[p][c] = 0.f;

    // decode staging pixel once (per-tap shift applied below)
    const int P_stage = tile * 64 + p_stage;
    const int b_s   = P_stage / (HG * WG);
    const int rem_s = P_stage % (HG * WG);
    const int iy_s  = rem_s / WG;
    const int jx_s  = rem_s % WG;

    const int nky = dy ? 1 : 2;
    const int nkx = dx ? 1 : 2;

    for (int ty = 0; ty < nky; ++ty) {
        const int di   = dy ? 0 : (ty == 0 ? -1 : 0);
        const int krow = dy ? 1 : (ty == 0 ?  2 : 0);   // = 2-ki
        for (int tx = 0; tx < nkx; ++tx) {
            const int dj   = dx ? 0 : (tx == 0 ? -1 : 0);
            const int kcol = dx ? 1 : (tx == 0 ?  2 : 0);
            const float* __restrict__ wtap = wt + (krow * 3 + kcol) * Cc * Cc;

            const int gi = iy_s + di, gj = jx_s + dj;
            const bool valid = (gi >= 0) && (gj >= 0);
            const float* __restrict__ gsrc = g + (size_t)(((b_s * HG + gi) * WG + gj)) * Cc;

            for (int co0 = 0; co0 < Cc; co0 += 16) {
                __syncthreads();
                // stage weights: thread t owns ci row t, co0..co0+15 (64B line)
                {
                    const float* src = wtap + t * Cc + co0;
                    float4 a0 = *(const float4*)(src + 0);
                    float4 a1 = *(const float4*)(src + 4);
                    float4 a2 = *(const float4*)(src + 8);
                    float4 a3 = *(const float4*)(src + 12);
                    w_lds[ 0][t] = a0.x; w_lds[ 1][t] = a0.y; w_lds[ 2][t] = a0.z; w_lds[ 3][t] = a0.w;
                    w_lds[ 4][t] = a1.x; w_lds[ 5][t] = a1.y; w_lds[ 6][t] = a1.z; w_lds[ 7][t] = a1.w;
                    w_lds[ 8][t] = a2.x; w_lds[ 9][t] = a2.y; w_lds[10][t] = a2.z; w_lds[11][t] = a2.w;
                    w_lds[12][t] = a3.x; w_lds[13][t] = a3.y; w_lds[14][t] = a3.z; w_lds[15][t] = a3.w;
                }
                // stage g (zero-padded at boundary)
                {
                    float4 gv = make_float4(0.f, 0.f, 0.f, 0.f);
                    if (valid) gv = *(const float4*)(gsrc + co0 + co_off);
                    g_lds[co_off + 0][p_stage] = gv.x;
                    g_lds[co_off + 1][p_stage] = gv.y;
                    g_lds[co_off + 2][p_stage] = gv.z;
                    g_lds[co_off + 3][p_stage] = gv.w;
                }
                __syncthreads();
                #pragma unroll
                for (int co = 0; co < 16; ++co) {
                    float4 wv = *(const float4*)&w_lds[co][ci0];
                    float4 g0 = *(const float4*)&g_lds[co][pg * 16 + 0];
                    float4 g1 = *(const float4*)&g_lds[co][pg * 16 + 4];
                    float4 g2 = *(const float4*)&g_lds[co][pg * 16 + 8];
                    float4 g3 = *(const float4*)&g_lds[co][pg * 16 + 12];
                    float gs_[16] = {g0.x, g0.y, g0.z, g0.w,
                                     g1.x, g1.y, g1.z, g1.w,
                                     g2.x, g2.y, g2.z, g2.w,
                                     g3.x, g3.y, g3.z, g3.w};
                    #pragma unroll
                    for (int p = 0; p < 16; ++p) {
                        acc[p][0] += gs_[p] * wv.x;
                        acc[p][1] += gs_[p] * wv.y;
                        acc[p][2] += gs_[p] * wv.z;
                        acc[p][3] += gs_[p] * wv.w;
                    }
                }
            }
        }
    }

    // epilogue: write 16 pixels x 4 ci, coalesced float4
    #pragma unroll
    for (int p = 0; p < 16; ++p) {
        int P   = tile * 64 + pg * 16 + p;
        int b   = P / (HG * WG);
        int rem = P % (HG * WG);
        int iy  = rem / WG, jx = rem % WG;
        int y = 2 * iy + dy, x = 2 * jx + dx;
        float4 v = make_float4(acc[p][0], acc[p][1], acc[p][2], acc[p][3]);
        *(float4*)(out + (size_t)((b * HIN + y) * WIN + x) * Cc + ci0) = v;
    }
}

// grad_wt: 9 taps, C[ci,co] = sum_{b,i,j} X[pix,ci] * G[pix,co].
// grid = (4 tiles of 128x128, 9 taps, 32 batches); block = 256; atomics into pre-zeroed gw.
__global__ __launch_bounds__(256) void k_grad_wt(
    const float* __restrict__ g,      // [32,28,28,256]
    const float* __restrict__ inp,    // [32,56,56,256]
    float* __restrict__ gw)           // [3,3,256,256] (pre-zeroed)
{
    __shared__ float x_lds[16][128];
    __shared__ float gl[16][128];

    const int t   = threadIdx.x;
    const int tci = (blockIdx.x >> 1) * 128;
    const int tco = (blockIdx.x & 1) * 128;
    const int tap = blockIdx.y;
    const int ki = tap / 3, kj = tap % 3;
    const int b = blockIdx.z;

    const int kk_s = t >> 4;          // staging row 0..15
    const int c8   = (t & 15) * 8;    // staging col base
    const int ci_sub = (t >> 4) * 8;
    const int co_sub = (t & 15) * 8;

    float acc[8][8];
    #pragma unroll
    for (int a = 0; a < 8; ++a)
        #pragma unroll
        for (int c = 0; c < 8; ++c) acc[a][c] = 0.f;

    const float* __restrict__ gbase = g   + (size_t)b * HG * WG * Cc;
    const float* __restrict__ ibase = inp + (size_t)b * HIN * WIN * Cc;

    for (int chunk = 0; chunk < 49; ++chunk) {
        __syncthreads();
        const int p = chunk * 16 + kk_s;      // 0..783
        const int i = p / WG, j = p % WG;
        const int r = ki + 2 * i, s = kj + 2 * j;
        const bool valid = (r < HIN) && (s < WIN);
        float4 x0 = make_float4(0.f,0.f,0.f,0.f), x1 = x0;
        if (valid) {
            const float* xs = ibase + (size_t)(r * WIN + s) * Cc + tci + c8;
            x0 = *(const float4*)xs;
            x1 = *(const float4*)(xs + 4);
        }
        const float* gs = gbase + (size_t)p * Cc + tco + c8;
        float4 g0 = *(const float4*)gs;
        float4 g1 = *(const float4*)(gs + 4);
        *(float4*)&x_lds[kk_s][c8]     = x0;
        *(float4*)&x_lds[kk_s][c8 + 4] = x1;
        *(float4*)&gl[kk_s][c8]        = g0;
        *(float4*)&gl[kk_s][c8 + 4]    = g1;
        __syncthreads();
        #pragma unroll
        for (int kk = 0; kk < 16; ++kk) {
            float4 a0 = *(const float4*)&x_lds[kk][ci_sub];
            float4 a1 = *(const float4*)&x_lds[kk][ci_sub + 4];
            float4 b0 = *(const float4*)&gl[kk][co_sub];
            float4 b1 = *(const float4*)&gl[kk][co_sub + 4];
            float av[8] = {a0.x,a0.y,a0.z,a0.w, a1.x,a1.y,a1.z,a1.w};
            float bv[8] = {b0.x,b0.y,b0.z,b0.w, b1.x,b1.y,b1.z,b1.w};
            #pragma unroll
            for (int a = 0; a < 8; ++a)
                #pragma unroll
                for (int c = 0; c < 8; ++c)
                    acc[a][c] += av[a] * bv[c];
        }
    }

    #pragma unroll
    for (int a = 0; a < 8; ++a) {
        float* dst = gw + (size_t)(tap * Cc + tci + ci_sub + a) * Cc + tco + co_sub;
        #pragma unroll
        for (int c = 0; c < 8; ++c) atomicAdd(dst + c, acc[a][c]);
    }
}

// grad_bias: 98 blocks x 256 threads; thread t sums co=t over 256 pixels.
__global__ __launch_bounds__(256) void k_bias(
    const float* __restrict__ g, float* __restrict__ bias)
{
    const int t = threadIdx.x;
    const float* base = g + (size_t)blockIdx.x * 256 * Cc;
    float acc = 0.f;
    #pragma unroll 8
    for (int p = 0; p < 256; ++p) acc += base[(size_t)p * Cc + t];
    atomicAdd(bias + t, acc);
}

extern "C" void kernel_launch(void* const* d_in, const int* in_sizes, int n_in,
                              void* d_out, int out_size, void* d_ws, size_t ws_size,
                              hipStream_t stream) {
    const float* g   = (const float*)d_in[0];   // grad_output [32,28,28,256]
    const float* inp = (const float*)d_in[1];   // inputs      [32,56,56,256]
    const float* wt  = (const float*)d_in[2];   // kernels     [3,3,256,256]
    float* out = (float*)d_out;

    const int nzero = GW_SIZE + 256;
    k_zero<<<(nzero + 255) / 256, 256, 0, stream>>>(out + GW_OFF, nzero);
    k_grad_in<<<dim3(392, 4), 256, 0, stream>>>(g, wt, out);
    k_grad_wt<<<dim3(4, 9, 32), 256, 0, stream>>>(g, inp, out + GW_OFF);
    k_bias<<<98, 256, 0, stream>>>(g, out + BIAS_OFF);
}

// Round 2
// 336.704 us; speedup vs baseline: 3.3620x; 3.3620x over previous
//
#include <hip/hip_runtime.h>

#define Bn   32
#define HIN  56
#define WIN  56
#define Cc   256
#define HG   28
#define WG   28
#define NPIX (HG*WG)                    // 784

#define GIN_SIZE (Bn*HIN*WIN*Cc)        // 25690112
#define GW_SIZE  (9*Cc*Cc)              // 589824
#define GW_OFF   GIN_SIZE
#define BIAS_OFF (GW_OFF + GW_SIZE)

typedef short bf16x8 __attribute__((ext_vector_type(8)));
typedef float f32x4  __attribute__((ext_vector_type(4)));

__device__ __forceinline__ unsigned short f2bf(float f) {
    union { float f; unsigned int u; } v; v.f = f;
    unsigned int u = v.u;
    u += 0x7fffu + ((u >> 16) & 1u);    // RNE
    return (unsigned short)(u >> 16);
}

// element index into a [row][32] bf16 LDS tile with 16B-granule XOR swizzle.
// Write and read use the same function -> self-consistent.
__device__ __forceinline__ int swz(int row, int k) {
    int g2 = (k >> 3) ^ (row & 3) ^ ((row >> 2) & 3);
    return row * 32 + (g2 << 3) + (k & 7);
}

__global__ __launch_bounds__(256) void k_zero(float* __restrict__ p, int n) {
    int i = blockIdx.x * 256 + threadIdx.x;
    if (i < n) p[i] = 0.f;
}

// ---------------------------------------------------------------------------
// grad_in: per parity class, D[pix][ci] = sum_{tap,co} G_shift[pix][co]*W[ci][co]
// grid = (196 m-tiles of 128 pixels, 2 n-tiles of 128 ci, 4 classes), 256 thr.
// ---------------------------------------------------------------------------
__global__ __launch_bounds__(256) void k_grad_in(
    const float* __restrict__ g,      // [32,28,28,256]
    const float* __restrict__ wt,     // [3,3,256,256]
    float* __restrict__ out)          // [32,56,56,256]
{
    __shared__ unsigned short ga[128 * 32];   // [pix_local][k=co32]
    __shared__ unsigned short wb[128 * 32];   // [ci_local][k=co32]

    const int t    = threadIdx.x;
    const int l    = t & 63;
    const int wave = t >> 6;
    const int mbase = (wave & 1) * 64;
    const int nbase = (wave >> 1) * 64;
    const int q    = l >> 4;
    const int r16  = l & 15;

    const int mtile = blockIdx.x;
    const int ntile = blockIdx.y;
    const int cls   = blockIdx.z;
    const int dy = cls >> 1, dx = cls & 1;

    // staging identity: row = t>>1 (0..127), co half = (t&1)*16
    const int sp = t >> 1;
    const int sc = (t & 1) * 16;
    const int P_s   = mtile * 128 + sp;
    const int b_s   = P_s / NPIX;
    const int rem_s = P_s % NPIX;
    const int iy_s  = rem_s / WG;
    const int jx_s  = rem_s % WG;
    const int sci   = ntile * 128 + sp;       // B row: global ci

    f32x4 acc[4][4];
    #pragma unroll
    for (int a = 0; a < 4; ++a)
        #pragma unroll
        for (int b = 0; b < 4; ++b) acc[a][b] = (f32x4){0.f, 0.f, 0.f, 0.f};

    // hoisted fragment LDS offsets (chunk-invariant)
    int aoff[4], boff[4];
    #pragma unroll
    for (int mf = 0; mf < 4; ++mf) aoff[mf] = swz(mbase + mf * 16 + r16, q * 8);
    #pragma unroll
    for (int nf = 0; nf < 4; ++nf) boff[nf] = swz(nbase + nf * 16 + r16, q * 8);

    const int nky = dy ? 1 : 2;
    const int nkx = dx ? 1 : 2;

    for (int ty = 0; ty < nky; ++ty) {
        const int di   = dy ? 0 : (ty == 0 ? -1 : 0);
        const int krow = dy ? 1 : (ty == 0 ?  2 : 0);
        for (int tx = 0; tx < nkx; ++tx) {
            const int dj   = dx ? 0 : (tx == 0 ? -1 : 0);
            const int kcol = dx ? 1 : (tx == 0 ?  2 : 0);

            const int gi = iy_s + di, gj = jx_s + dj;
            const bool valid = (gi >= 0) && (gj >= 0);
            const float* __restrict__ gsrc = g + (size_t)((b_s * HG + gi) * WG + gj) * Cc + sc;
            const float* __restrict__ wsrc = wt + (size_t)((krow * 3 + kcol) * Cc + sci) * Cc + sc;

            #pragma unroll 1
            for (int co0 = 0; co0 < Cc; co0 += 32) {
                __syncthreads();
                // stage A (shifted grad_output), fp32 -> bf16
                {
                    float4 v0 = make_float4(0,0,0,0), v1 = v0, v2 = v0, v3 = v0;
                    if (valid) {
                        v0 = *(const float4*)(gsrc + co0 + 0);
                        v1 = *(const float4*)(gsrc + co0 + 4);
                        v2 = *(const float4*)(gsrc + co0 + 8);
                        v3 = *(const float4*)(gsrc + co0 + 12);
                    }
                    ushort4 u0 = {f2bf(v0.x), f2bf(v0.y), f2bf(v0.z), f2bf(v0.w)};
                    ushort4 u1 = {f2bf(v1.x), f2bf(v1.y), f2bf(v1.z), f2bf(v1.w)};
                    ushort4 u2 = {f2bf(v2.x), f2bf(v2.y), f2bf(v2.z), f2bf(v2.w)};
                    ushort4 u3 = {f2bf(v3.x), f2bf(v3.y), f2bf(v3.z), f2bf(v3.w)};
                    *(ushort4*)&ga[swz(sp, sc + 0)]  = u0;
                    *(ushort4*)&ga[swz(sp, sc + 4)]  = u1;
                    *(ushort4*)&ga[swz(sp, sc + 8)]  = u2;
                    *(ushort4*)&ga[swz(sp, sc + 12)] = u3;
                }
                // stage B (weights W[ci][co], co contiguous)
                {
                    float4 v0 = *(const float4*)(wsrc + co0 + 0);
                    float4 v1 = *(const float4*)(wsrc + co0 + 4);
                    float4 v2 = *(const float4*)(wsrc + co0 + 8);
                    float4 v3 = *(const float4*)(wsrc + co0 + 12);
                    ushort4 u0 = {f2bf(v0.x), f2bf(v0.y), f2bf(v0.z), f2bf(v0.w)};
                    ushort4 u1 = {f2bf(v1.x), f2bf(v1.y), f2bf(v1.z), f2bf(v1.w)};
                    ushort4 u2 = {f2bf(v2.x), f2bf(v2.y), f2bf(v2.z), f2bf(v2.w)};
                    ushort4 u3 = {f2bf(v3.x), f2bf(v3.y), f2bf(v3.z), f2bf(v3.w)};
                    *(ushort4*)&wb[swz(sp, sc + 0)]  = u0;
                    *(ushort4*)&wb[swz(sp, sc + 4)]  = u1;
                    *(ushort4*)&wb[swz(sp, sc + 8)]  = u2;
                    *(ushort4*)&wb[swz(sp, sc + 12)] = u3;
                }
                __syncthreads();

                bf16x8 af[4], bf[4];
                #pragma unroll
                for (int mf = 0; mf < 4; ++mf) af[mf] = *(const bf16x8*)&ga[aoff[mf]];
                #pragma unroll
                for (int nf = 0; nf < 4; ++nf) bf[nf] = *(const bf16x8*)&wb[boff[nf]];
                #pragma unroll
                for (int mf = 0; mf < 4; ++mf)
                    #pragma unroll
                    for (int nf = 0; nf < 4; ++nf)
                        acc[mf][nf] = __builtin_amdgcn_mfma_f32_16x16x32_bf16(
                            af[mf], bf[nf], acc[mf][nf], 0, 0, 0);
            }
        }
    }

    // epilogue: D row = pixel (4*(l>>4)+reg within 16), col = ci (l&15)
    #pragma unroll
    for (int mf = 0; mf < 4; ++mf) {
        #pragma unroll
        for (int rr = 0; rr < 4; ++rr) {
            const int P   = mtile * 128 + mbase + mf * 16 + q * 4 + rr;
            const int b   = P / NPIX;
            const int rem = P % NPIX;
            const int iy  = rem / WG, jx = rem % WG;
            const int y = 2 * iy + dy, x = 2 * jx + dx;
            float* orow = out + (size_t)((b * HIN + y) * WIN + x) * Cc
                              + ntile * 128 + nbase + r16;
            #pragma unroll
            for (int nf = 0; nf < 4; ++nf) orow[nf * 16] = acc[mf][nf][rr];
        }
    }
}

// ---------------------------------------------------------------------------
// grad_wt: per tap, C[ci][co] = sum_p X[p][ci] * G[p][co]; split-K over batch
// pairs. grid = (4 128x128-tiles, 9 taps, 16 batch-pairs), 256 thr, atomics.
// ---------------------------------------------------------------------------
__global__ __launch_bounds__(256) void k_grad_wt(
    const float* __restrict__ g,      // [32,28,28,256]
    const float* __restrict__ inp,    // [32,56,56,256]
    float* __restrict__ gw)           // [3,3,256,256] pre-zeroed
{
    __shared__ unsigned short xa[128 * 32];   // [ci_local][k=pix32]
    __shared__ unsigned short xg[128 * 32];   // [co_local][k=pix32]

    const int t    = threadIdx.x;
    const int l    = t & 63;
    const int wave = t >> 6;
    const int mbase = (wave & 1) * 64;        // ci
    const int nbase = (wave >> 1) * 64;       // co
    const int q    = l >> 4;
    const int r16  = l & 15;

    const int tci = (blockIdx.x >> 1) * 128;
    const int tco = (blockIdx.x & 1) * 128;
    const int tap = blockIdx.y;
    const int ki = tap / 3, kj = tap % 3;
    const int bz = blockIdx.z;                // batches 2bz, 2bz+1

    // staging identity: pixel pair pp=2*(t>>4), channel = (t&15)+16j
    const int pp = (t >> 4) * 2;
    const int c0 = t & 15;

    f32x4 acc[4][4];
    #pragma unroll
    for (int a = 0; a < 4; ++a)
        #pragma unroll
        for (int b = 0; b < 4; ++b) acc[a][b] = (f32x4){0.f, 0.f, 0.f, 0.f};

    int aoff[4], boff[4];
    #pragma unroll
    for (int mf = 0; mf < 4; ++mf) aoff[mf] = swz(mbase + mf * 16 + r16, q * 8);
    #pragma unroll
    for (int nf = 0; nf < 4; ++nf) boff[nf] = swz(nbase + nf * 16 + r16, q * 8);

    for (int bb = 0; bb < 2; ++bb) {
        const int b = bz * 2 + bb;
        const float* __restrict__ gb = g   + (size_t)b * NPIX * Cc;
        const float* __restrict__ ib = inp + (size_t)b * HIN * WIN * Cc;

        #pragma unroll 1
        for (int cc = 0; cc < 25; ++cc) {
            const int pA = cc * 32 + pp;
            const int pB = pA + 1;
            // decode X pixels
            const int iA = pA / WG, jA = pA % WG;
            const int iB = pB / WG, jB = pB % WG;
            const int rA = ki + 2 * iA, sA = kj + 2 * jA;
            const int rB = ki + 2 * iB, sB = kj + 2 * jB;
            const bool vxA = (pA < NPIX) && (rA < HIN) && (sA < WIN);
            const bool vxB = (pB < NPIX) && (rB < HIN) && (sB < WIN);
            const bool vgA = (pA < NPIX);
            const bool vgB = (pB < NPIX);
            const float* __restrict__ xs0 = ib + (size_t)(rA * WIN + sA) * Cc + tci + c0;
            const float* __restrict__ xs1 = ib + (size_t)(rB * WIN + sB) * Cc + tci + c0;
            const float* __restrict__ gs0 = gb + (size_t)pA * Cc + tco + c0;
            const float* __restrict__ gs1 = gb + (size_t)pB * Cc + tco + c0;

            __syncthreads();
            #pragma unroll
            for (int j = 0; j < 8; ++j) {
                const int ch = c0 + 16 * j;
                float x0 = vxA ? xs0[16 * j] : 0.f;
                float x1 = vxB ? xs1[16 * j] : 0.f;
                *(unsigned int*)&xa[swz(ch, pp)] =
                    (unsigned int)f2bf(x0) | ((unsigned int)f2bf(x1) << 16);
                float g0 = vgA ? gs0[16 * j] : 0.f;
                float g1 = vgB ? gs1[16 * j] : 0.f;
                *(unsigned int*)&xg[swz(ch, pp)] =
                    (unsigned int)f2bf(g0) | ((unsigned int)f2bf(g1) << 16);
            }
            __syncthreads();

            bf16x8 af[4], bfr[4];
            #pragma unroll
            for (int mf = 0; mf < 4; ++mf) af[mf] = *(const bf16x8*)&xa[aoff[mf]];
            #pragma unroll
            for (int nf = 0; nf < 4; ++nf) bfr[nf] = *(const bf16x8*)&xg[boff[nf]];
            #pragma unroll
            for (int mf = 0; mf < 4; ++mf)
                #pragma unroll
                for (int nf = 0; nf < 4; ++nf)
                    acc[mf][nf] = __builtin_amdgcn_mfma_f32_16x16x32_bf16(
                        af[mf], bfr[nf], acc[mf][nf], 0, 0, 0);
        }
    }

    // epilogue: row = ci, col = co
    #pragma unroll
    for (int mf = 0; mf < 4; ++mf) {
        #pragma unroll
        for (int rr = 0; rr < 4; ++rr) {
            const int cirow = tci + mbase + mf * 16 + q * 4 + rr;
            float* dst = gw + (size_t)(tap * Cc + cirow) * Cc + tco + nbase + r16;
            #pragma unroll
            for (int nf = 0; nf < 4; ++nf) atomicAdd(dst + nf * 16, acc[mf][nf][rr]);
        }
    }
}

__global__ __launch_bounds__(256) void k_bias(
    const float* __restrict__ g, float* __restrict__ bias)
{
    const int t = threadIdx.x;
    const float* base = g + (size_t)blockIdx.x * 256 * Cc;
    float acc = 0.f;
    #pragma unroll 8
    for (int p = 0; p < 256; ++p) acc += base[(size_t)p * Cc + t];
    atomicAdd(bias + t, acc);
}

extern "C" void kernel_launch(void* const* d_in, const int* in_sizes, int n_in,
                              void* d_out, int out_size, void* d_ws, size_t ws_size,
                              hipStream_t stream) {
    const float* g   = (const float*)d_in[0];
    const float* inp = (const float*)d_in[1];
    const float* wt  = (const float*)d_in[2];
    float* out = (float*)d_out;

    const int nzero = GW_SIZE + 256;
    k_zero<<<(nzero + 255) / 256, 256, 0, stream>>>(out + GW_OFF, nzero);
    k_grad_in<<<dim3(196, 2, 4), 256, 0, stream>>>(g, wt, out);
    k_grad_wt<<<dim3(4, 9, 16), 256, 0, stream>>>(g, inp, out + GW_OFF);
    k_bias<<<98, 256, 0, stream>>>(g, out + BIAS_OFF);
}

// Round 3
// 206.984 us; speedup vs baseline: 5.4690x; 1.6267x over previous
//
#include <hip/hip_runtime.h>

#define Bn   32
#define HIN  56
#define WIN  56
#define Cc   256
#define HG   28
#define WG   28
#define NPIX (HG*WG)                    // 784

#define GIN_SIZE (Bn*HIN*WIN*Cc)        // 25690112
#define GW_SIZE  (9*Cc*Cc)              // 589824
#define GW_OFF   GIN_SIZE
#define BIAS_OFF (GW_OFF + GW_SIZE)

typedef short bf16x8 __attribute__((ext_vector_type(8)));
typedef float f32x4  __attribute__((ext_vector_type(4)));

__device__ __forceinline__ unsigned short f2bf(float f) {
    union { float f; unsigned int u; } v; v.f = f;
    unsigned int u = v.u;
    u += 0x7fffu + ((u >> 16) & 1u);    // RNE
    return (unsigned short)(u >> 16);
}

// [row][32] bf16 tile, 16B-granule XOR swizzle (k_grad_in, proven R1)
__device__ __forceinline__ int swz(int row, int k) {
    int g2 = (k >> 3) ^ (row & 3) ^ ((row >> 2) & 3);
    return row * 32 + (g2 << 3) + (k & 7);
}

// [row][64] bf16 tile (rows = 128B -> row index bank-dead), 16B-granule XOR.
// Fragment read (b128, one granule) sees distinct granules per 8-lane phase.
__device__ __forceinline__ int swz64(int row, int k) {
    int gq = ((k >> 3) ^ (row & 7) ^ ((row >> 4) & 7)) & 7;
    return row * 64 + (gq << 3) + (k & 7);
}

__global__ __launch_bounds__(256) void k_zero(float* __restrict__ p, int n) {
    int i = blockIdx.x * 256 + threadIdx.x;
    if (i < n) p[i] = 0.f;
}

// ---------------------------------------------------------------------------
// grad_in: per parity class, D[pix][ci] = sum_{tap,co} G_shift[pix][co]*W[ci][co]
// (unchanged from R1 — verified, ~fast)
// ---------------------------------------------------------------------------
__global__ __launch_bounds__(256) void k_grad_in(
    const float* __restrict__ g,      // [32,28,28,256]
    const float* __restrict__ wt,     // [3,3,256,256]
    float* __restrict__ out)          // [32,56,56,256]
{
    __shared__ unsigned short ga[128 * 32];   // [pix_local][k=co32]
    __shared__ unsigned short wb[128 * 32];   // [ci_local][k=co32]

    const int t    = threadIdx.x;
    const int l    = t & 63;
    const int wave = t >> 6;
    const int mbase = (wave & 1) * 64;
    const int nbase = (wave >> 1) * 64;
    const int q    = l >> 4;
    const int r16  = l & 15;

    const int mtile = blockIdx.x;
    const int ntile = blockIdx.y;
    const int cls   = blockIdx.z;
    const int dy = cls >> 1, dx = cls & 1;

    const int sp = t >> 1;
    const int sc = (t & 1) * 16;
    const int P_s   = mtile * 128 + sp;
    const int b_s   = P_s / NPIX;
    const int rem_s = P_s % NPIX;
    const int iy_s  = rem_s / WG;
    const int jx_s  = rem_s % WG;
    const int sci   = ntile * 128 + sp;

    f32x4 acc[4][4];
    #pragma unroll
    for (int a = 0; a < 4; ++a)
        #pragma unroll
        for (int b = 0; b < 4; ++b) acc[a][b] = (f32x4){0.f, 0.f, 0.f, 0.f};

    int aoff[4], boff[4];
    #pragma unroll
    for (int mf = 0; mf < 4; ++mf) aoff[mf] = swz(mbase + mf * 16 + r16, q * 8);
    #pragma unroll
    for (int nf = 0; nf < 4; ++nf) boff[nf] = swz(nbase + nf * 16 + r16, q * 8);

    const int nky = dy ? 1 : 2;
    const int nkx = dx ? 1 : 2;

    for (int ty = 0; ty < nky; ++ty) {
        const int di   = dy ? 0 : (ty == 0 ? -1 : 0);
        const int krow = dy ? 1 : (ty == 0 ?  2 : 0);
        for (int tx = 0; tx < nkx; ++tx) {
            const int dj   = dx ? 0 : (tx == 0 ? -1 : 0);
            const int kcol = dx ? 1 : (tx == 0 ?  2 : 0);

            const int gi = iy_s + di, gj = jx_s + dj;
            const bool valid = (gi >= 0) && (gj >= 0);
            const float* __restrict__ gsrc = g + (size_t)((b_s * HG + gi) * WG + gj) * Cc + sc;
            const float* __restrict__ wsrc = wt + (size_t)((krow * 3 + kcol) * Cc + sci) * Cc + sc;

            #pragma unroll 1
            for (int co0 = 0; co0 < Cc; co0 += 32) {
                __syncthreads();
                {
                    float4 v0 = make_float4(0,0,0,0), v1 = v0, v2 = v0, v3 = v0;
                    if (valid) {
                        v0 = *(const float4*)(gsrc + co0 + 0);
                        v1 = *(const float4*)(gsrc + co0 + 4);
                        v2 = *(const float4*)(gsrc + co0 + 8);
                        v3 = *(const float4*)(gsrc + co0 + 12);
                    }
                    ushort4 u0 = {f2bf(v0.x), f2bf(v0.y), f2bf(v0.z), f2bf(v0.w)};
                    ushort4 u1 = {f2bf(v1.x), f2bf(v1.y), f2bf(v1.z), f2bf(v1.w)};
                    ushort4 u2 = {f2bf(v2.x), f2bf(v2.y), f2bf(v2.z), f2bf(v2.w)};
                    ushort4 u3 = {f2bf(v3.x), f2bf(v3.y), f2bf(v3.z), f2bf(v3.w)};
                    *(ushort4*)&ga[swz(sp, sc + 0)]  = u0;
                    *(ushort4*)&ga[swz(sp, sc + 4)]  = u1;
                    *(ushort4*)&ga[swz(sp, sc + 8)]  = u2;
                    *(ushort4*)&ga[swz(sp, sc + 12)] = u3;
                }
                {
                    float4 v0 = *(const float4*)(wsrc + co0 + 0);
                    float4 v1 = *(const float4*)(wsrc + co0 + 4);
                    float4 v2 = *(const float4*)(wsrc + co0 + 8);
                    float4 v3 = *(const float4*)(wsrc + co0 + 12);
                    ushort4 u0 = {f2bf(v0.x), f2bf(v0.y), f2bf(v0.z), f2bf(v0.w)};
                    ushort4 u1 = {f2bf(v1.x), f2bf(v1.y), f2bf(v1.z), f2bf(v1.w)};
                    ushort4 u2 = {f2bf(v2.x), f2bf(v2.y), f2bf(v2.z), f2bf(v2.w)};
                    ushort4 u3 = {f2bf(v3.x), f2bf(v3.y), f2bf(v3.z), f2bf(v3.w)};
                    *(ushort4*)&wb[swz(sp, sc + 0)]  = u0;
                    *(ushort4*)&wb[swz(sp, sc + 4)]  = u1;
                    *(ushort4*)&wb[swz(sp, sc + 8)]  = u2;
                    *(ushort4*)&wb[swz(sp, sc + 12)] = u3;
                }
                __syncthreads();

                bf16x8 af[4], bf[4];
                #pragma unroll
                for (int mf = 0; mf < 4; ++mf) af[mf] = *(const bf16x8*)&ga[aoff[mf]];
                #pragma unroll
                for (int nf = 0; nf < 4; ++nf) bf[nf] = *(const bf16x8*)&wb[boff[nf]];
                #pragma unroll
                for (int mf = 0; mf < 4; ++mf)
                    #pragma unroll
                    for (int nf = 0; nf < 4; ++nf)
                        acc[mf][nf] = __builtin_amdgcn_mfma_f32_16x16x32_bf16(
                            af[mf], bf[nf], acc[mf][nf], 0, 0, 0);
            }
        }
    }

    #pragma unroll
    for (int mf = 0; mf < 4; ++mf) {
        #pragma unroll
        for (int rr = 0; rr < 4; ++rr) {
            const int P   = mtile * 128 + mbase + mf * 16 + q * 4 + rr;
            const int b   = P / NPIX;
            const int rem = P % NPIX;
            const int iy  = rem / WG, jx = rem % WG;
            const int y = 2 * iy + dy, x = 2 * jx + dx;
            float* orow = out + (size_t)((b * HIN + y) * WIN + x) * Cc
                              + ntile * 128 + nbase + r16;
            #pragma unroll
            for (int nf = 0; nf < 4; ++nf) orow[nf * 16] = acc[mf][nf][rr];
        }
    }
}

// ---------------------------------------------------------------------------
// grad_wt v2: per tap, C[ci][co] = sum_p X[p][ci] * G[p][co].
// In-register transpose: thread loads 8 pix x 4 ch as float4s, repacks to
// 4x bf16x8 (one ds_write_b128 per ch row). K-chunk 64. Split-K per batch.
// grid = (4 128x128-tiles, 9 taps, 32 batches), 256 thr, atomics.
// ---------------------------------------------------------------------------
__global__ __launch_bounds__(256) void k_grad_wt(
    const float* __restrict__ g,      // [32,28,28,256]
    const float* __restrict__ inp,    // [32,56,56,256]
    float* __restrict__ gw)           // [3,3,256,256] pre-zeroed
{
    __shared__ unsigned short xa[128 * 64];   // [ci_local][pix64] swizzled
    __shared__ unsigned short xg[128 * 64];   // [co_local][pix64] swizzled

    const int t    = threadIdx.x;
    const int l    = t & 63;
    const int wave = t >> 6;
    const int mbase = (wave & 1) * 64;        // ci
    const int nbase = (wave >> 1) * 64;       // co
    const int q    = l >> 4;
    const int r16  = l & 15;

    const int tci = (blockIdx.x >> 1) * 128;
    const int tco = (blockIdx.x & 1) * 128;
    const int tap = blockIdx.y;
    const int ki = tap / 3, kj = tap % 3;
    const int b  = blockIdx.z;

    // staging: thread owns pixels p0..p0+7, channels c4..c4+3
    const int pg = t >> 5;                    // 0..7
    const int p0 = pg * 8;
    const int c4 = (t & 31) * 4;              // 0..124

    f32x4 acc[4][4];
    #pragma unroll
    for (int a = 0; a < 4; ++a)
        #pragma unroll
        for (int c = 0; c < 4; ++c) acc[a][c] = (f32x4){0.f, 0.f, 0.f, 0.f};

    int aoff[2][4], boff[2][4];
    #pragma unroll
    for (int kk = 0; kk < 2; ++kk) {
        #pragma unroll
        for (int mf = 0; mf < 4; ++mf) {
            aoff[kk][mf] = swz64(mbase + mf * 16 + r16, kk * 32 + q * 8);
            boff[kk][mf] = swz64(nbase + mf * 16 + r16, kk * 32 + q * 8);
        }
    }

    const float* __restrict__ gb = g   + (size_t)b * NPIX * Cc;
    const float* __restrict__ ib = inp + (size_t)b * HIN * WIN * Cc;

    #pragma unroll 1
    for (int cc = 0; cc < 13; ++cc) {
        __syncthreads();
        // ---- stage X (in-register transpose) ----
        {
            bf16x8 wx[4];
            #pragma unroll
            for (int j = 0; j < 8; ++j) {
                const int p  = cc * 64 + p0 + j;
                const int i  = p / WG, jx = p % WG;
                const int r  = ki + 2 * i, s = kj + 2 * jx;
                const bool v = (p < NPIX) && (r < HIN) && (s < WIN);
                float4 xv = make_float4(0.f, 0.f, 0.f, 0.f);
                if (v) xv = *(const float4*)(ib + (size_t)(r * WIN + s) * Cc + tci + c4);
                wx[0][j] = (short)f2bf(xv.x);
                wx[1][j] = (short)f2bf(xv.y);
                wx[2][j] = (short)f2bf(xv.z);
                wx[3][j] = (short)f2bf(xv.w);
            }
            #pragma unroll
            for (int c = 0; c < 4; ++c)
                *(bf16x8*)&xa[swz64(c4 + c, p0)] = wx[c];
        }
        // ---- stage G (in-register transpose) ----
        {
            bf16x8 wgv[4];
            #pragma unroll
            for (int j = 0; j < 8; ++j) {
                const int p  = cc * 64 + p0 + j;
                const bool v = (p < NPIX);
                float4 gv = make_float4(0.f, 0.f, 0.f, 0.f);
                if (v) gv = *(const float4*)(gb + (size_t)p * Cc + tco + c4);
                wgv[0][j] = (short)f2bf(gv.x);
                wgv[1][j] = (short)f2bf(gv.y);
                wgv[2][j] = (short)f2bf(gv.z);
                wgv[3][j] = (short)f2bf(gv.w);
            }
            #pragma unroll
            for (int c = 0; c < 4; ++c)
                *(bf16x8*)&xg[swz64(c4 + c, p0)] = wgv[c];
        }
        __syncthreads();

        #pragma unroll
        for (int kk = 0; kk < 2; ++kk) {
            bf16x8 af[4], bfr[4];
            #pragma unroll
            for (int mf = 0; mf < 4; ++mf) af[mf]  = *(const bf16x8*)&xa[aoff[kk][mf]];
            #pragma unroll
            for (int nf = 0; nf < 4; ++nf) bfr[nf] = *(const bf16x8*)&xg[boff[kk][nf]];
            #pragma unroll
            for (int mf = 0; mf < 4; ++mf)
                #pragma unroll
                for (int nf = 0; nf < 4; ++nf)
                    acc[mf][nf] = __builtin_amdgcn_mfma_f32_16x16x32_bf16(
                        af[mf], bfr[nf], acc[mf][nf], 0, 0, 0);
        }
    }

    // epilogue: row = ci (4q+reg), col = co (r16)
    #pragma unroll
    for (int mf = 0; mf < 4; ++mf) {
        #pragma unroll
        for (int rr = 0; rr < 4; ++rr) {
            const int cirow = tci + mbase + mf * 16 + q * 4 + rr;
            float* dst = gw + (size_t)(tap * Cc + cirow) * Cc + tco + nbase + r16;
            #pragma unroll
            for (int nf = 0; nf < 4; ++nf) atomicAdd(dst + nf * 16, acc[mf][nf][rr]);
        }
    }
}

__global__ __launch_bounds__(256) void k_bias(
    const float* __restrict__ g, float* __restrict__ bias)
{
    const int t = threadIdx.x;
    const float* base = g + (size_t)blockIdx.x * 256 * Cc;
    float acc = 0.f;
    #pragma unroll 8
    for (int p = 0; p < 256; ++p) acc += base[(size_t)p * Cc + t];
    atomicAdd(bias + t, acc);
}

extern "C" void kernel_launch(void* const* d_in, const int* in_sizes, int n_in,
                              void* d_out, int out_size, void* d_ws, size_t ws_size,
                              hipStream_t stream) {
    const float* g   = (const float*)d_in[0];
    const float* inp = (const float*)d_in[1];
    const float* wt  = (const float*)d_in[2];
    float* out = (float*)d_out;

    const int nzero = GW_SIZE + 256;
    k_zero<<<(nzero + 255) / 256, 256, 0, stream>>>(out + GW_OFF, nzero);
    k_grad_in<<<dim3(196, 2, 4), 256, 0, stream>>>(g, wt, out);
    k_grad_wt<<<dim3(4, 9, 32), 256, 0, stream>>>(g, inp, out + GW_OFF);
    k_bias<<<98, 256, 0, stream>>>(g, out + BIAS_OFF);
}